// Round 2
// baseline (863.881 us; speedup 1.0000x reference)
//
#include <hip/hip_runtime.h>

#define NN 128
#define NITER 300
#define NROUND 4   // bracket /5^4 = /625, then TWO exact active-set Newton steps

typedef __attribute__((ext_vector_type(2))) float v2f;

// ---- packed-f32 VOP3P helpers ----
// Operands now guaranteed in arch VGPRs (Q is 64 v2f/lane = 128 VGPR), so the
// "v" constraints no longer force accvgpr_read/write shuttles.
__device__ __forceinline__ long long pack_ss(float lo, float hi) {
  return (long long)(((unsigned long long)(unsigned)__float_as_int(hi) << 32)
                   | (unsigned long long)(unsigned)__float_as_int(lo));
}
__device__ __forceinline__ void pk_fma_s(v2f& acc, v2f a, long long b) {
  asm("v_pk_fma_f32 %0, %1, %2, %0" : "+v"(acc) : "v"(a), "s"(b));
}
__device__ __forceinline__ void pk_fma_v(v2f& acc, v2f a, v2f b) {
  asm("v_pk_fma_f32 %0, %1, %2, %0" : "+v"(acc) : "v"(a), "v"(b));
}
__device__ __forceinline__ v2f pk_mul_s(v2f a, long long b) {
  v2f d; asm("v_pk_mul_f32 %0, %1, %2" : "=v"(d) : "v"(a), "s"(b)); return d;
}

// ---- DPP wave-64 cross-lane helpers (R5-proven) ----
template<int CTRL>
__device__ __forceinline__ float dpp0(float x) {  // invalid lanes contribute 0
  return __int_as_float(__builtin_amdgcn_update_dpp(0, __float_as_int(x), CTRL, 0xF, 0xF, true));
}
template<int CTRL>
__device__ __forceinline__ float dppS(float x) {  // invalid lanes keep self
  int xi = __float_as_int(x);
  return __int_as_float(__builtin_amdgcn_update_dpp(xi, xi, CTRL, 0xF, 0xF, false));
}
__device__ __forceinline__ float bcast63(float x) {
  return __int_as_float(__builtin_amdgcn_readlane(__float_as_int(x), 63));
}
__device__ __forceinline__ float rlane(float x, int l) {   // l literal after unroll
  return __int_as_float(__builtin_amdgcn_readlane(__float_as_int(x), l));
}
__device__ __forceinline__ float wsum(float x) {
  x += dpp0<0x111>(x); x += dpp0<0x112>(x); x += dpp0<0x114>(x);
  x += dpp0<0x118>(x); x += dpp0<0x142>(x); x += dpp0<0x143>(x);
  return bcast63(x);
}
__device__ __forceinline__ void wsum2(float& x, float& y) {  // two interleaved chains
  float a = x, b = y;
  a += dpp0<0x111>(a); b += dpp0<0x111>(b);
  a += dpp0<0x112>(a); b += dpp0<0x112>(b);
  a += dpp0<0x114>(a); b += dpp0<0x114>(b);
  a += dpp0<0x118>(a); b += dpp0<0x118>(b);
  a += dpp0<0x142>(a); b += dpp0<0x142>(b);
  a += dpp0<0x143>(a); b += dpp0<0x143>(b);
  x = bcast63(a); y = bcast63(b);
}
__device__ __forceinline__ void wsum4(float& a, float& b, float& c, float& d) {
  a += dpp0<0x111>(a); b += dpp0<0x111>(b); c += dpp0<0x111>(c); d += dpp0<0x111>(d);
  a += dpp0<0x112>(a); b += dpp0<0x112>(b); c += dpp0<0x112>(c); d += dpp0<0x112>(d);
  a += dpp0<0x114>(a); b += dpp0<0x114>(b); c += dpp0<0x114>(c); d += dpp0<0x114>(d);
  a += dpp0<0x118>(a); b += dpp0<0x118>(b); c += dpp0<0x118>(c); d += dpp0<0x118>(d);
  a += dpp0<0x142>(a); b += dpp0<0x142>(b); c += dpp0<0x142>(c); d += dpp0<0x142>(d);
  a += dpp0<0x143>(a); b += dpp0<0x143>(b); c += dpp0<0x143>(c); d += dpp0<0x143>(d);
  a = bcast63(a); b = bcast63(b); c = bcast63(c); d = bcast63(d);
}
__device__ __forceinline__ void wminmax(float& mn, float& mx) {  // interleaved
  mn = fminf(mn, dppS<0x111>(mn)); mx = fmaxf(mx, dppS<0x111>(mx));
  mn = fminf(mn, dppS<0x112>(mn)); mx = fmaxf(mx, dppS<0x112>(mx));
  mn = fminf(mn, dppS<0x114>(mn)); mx = fmaxf(mx, dppS<0x114>(mx));
  mn = fminf(mn, dppS<0x118>(mn)); mx = fmaxf(mx, dppS<0x118>(mx));
  mn = fminf(mn, dppS<0x142>(mn)); mx = fmaxf(mx, dppS<0x142>(mx));
  mn = fminf(mn, dppS<0x143>(mn)); mx = fmaxf(mx, dppS<0x143>(mx));
  mn = bcast63(mn); mx = bcast63(mx);
}

// TWO WAVES PER SAMPLE, even/odd row split:
//   wave wid (0/1), lane l owns row r = 2*l + wid of Q (64 v2f column-pairs,
//   128 arch VGPRs -> no AGPR spill). Coordinate state (y/w, 2 coords/lane:
//   2l, 2l+1) is DUPLICATED in both waves; only the matvec outputs cross waves
//   (double-buffered LDS, ONE __syncthreads per iteration). The serial
//   projection chains of one block's waves overlap with the other resident
//   block's waves on the same SIMD (2 waves/SIMD).
__launch_bounds__(128, 2)
__global__ void markowitz_kernel(const float* __restrict__ rets,
                                 const float* __restrict__ cov,
                                 const float* __restrict__ gam,
                                 const float* __restrict__ alp,
                                 float* __restrict__ out)
{
  const int b    = blockIdx.x;
  const int tid  = threadIdx.x;
  const int wid  = tid >> 6;         // 0: even rows, 1: odd rows
  const int lane = tid & 63;

  __shared__ float pbuf[2][NN];      // matvec outputs, double-buffered
  __shared__ float fb[2];            // Frobenius half-sums

  const float g   = gam[b];
  const float g2  = g * g;
  const float aab = fabsf(alp[b]);
  const v2f* cb2 = (const v2f*)(cov + (size_t)b * (NN * NN));

  // ---------- build row r of Q = g2*C^T C + aab*I (column pairs) ----------
  v2f q[64];
  #pragma unroll
  for (int j = 0; j < 64; ++j) { v2f z = {0.f, 0.f}; q[j] = z; }

  // 2-row-deep prefetch; v2f load gives {C[k][2l], C[k][2l+1]} -> the row
  // multiplier C[k][r] is just c.x (wave0) / c.y (wave1): no extra load.
  v2f c0 = cb2[lane];
  v2f c1 = cb2[64 + lane];
  #pragma unroll 2
  for (int k = 0; k < NN; ++k) {
    v2f c = c0; c0 = c1;
    int kp = (k + 2 < NN) ? (k + 2) : (NN - 1);
    c1 = cb2[(size_t)kp * 64 + lane];
    float aown = wid ? c.y : c.x;          // C[k][r], r = 2*lane+wid
    v2f aw = { aown, aown };
    #pragma unroll
    for (int j = 0; j < 64; ++j) {
      long long sp = pack_ss(rlane(c.x, j), rlane(c.y, j));  // {C[k][2j],C[k][2j+1]}
      pk_fma_s(q[j], aw, sp);
    }
  }

  // scale by g2, diagonal, Frobenius^2 (2 packed partial chains)
  const long long g2p = pack_ss(g2, g2);
  v2f f0 = {0.f,0.f}, f1 = {0.f,0.f};
  const float dx = wid ? 0.f : aab;        // diag lands at pair j==lane, comp wid
  const float dy = wid ? aab : 0.f;
  #pragma unroll
  for (int j = 0; j < 64; ++j) {
    v2f qq = pk_mul_s(q[j], g2p);
    if (j == lane) { qq.x += dx; qq.y += dy; }
    q[j] = qq;
    if (j & 1) pk_fma_v(f0, qq, qq); else pk_fma_v(f1, qq, qq);
  }
  // cross-wave Frobenius combine
  {
    float shalf = wsum((f0.x + f1.x) + (f0.y + f1.y));
    if (lane == 0) fb[wid] = shalf;
  }
  __syncthreads();
  const float S    = fb[0] + fb[1];
  const float step = 0.5f / sqrtf(S);      // 1/(2||Q||_F)
  const float sc   = 2.f * step;
  const long long scp = pack_ss(sc, sc);
  #pragma unroll
  for (int j = 0; j < 64; ++j) q[j] = pk_mul_s(q[j], scp);   // q = 2*step*Q row

  v2f rr = ((const v2f*)rets)[(size_t)b * 64 + lane];
  const float r2e = step * rr.x;
  const float r2o = step * rr.y;

  // ---------- FISTA ----------
  float ye = 1.f / 128.f, yo = 1.f / 128.f;   // full coord state (2l, 2l+1), duplicated
  float wpe = ye, wpo = yo;
  float t_f = 1.f;

  #pragma unroll 1
  for (int it = 0; it < NITER; ++it) {
    // matvec: row r only. 128 rlane + 64 pk_fma, 2 interleaved chains.
    v2f s0 = {0.f,0.f}, s1 = {0.f,0.f};
    #pragma unroll
    for (int j = 0; j < 64; j += 2) {
      long long p0 = pack_ss(rlane(ye, j),     rlane(yo, j));
      long long p1 = pack_ss(rlane(ye, j + 1), rlane(yo, j + 1));
      pk_fma_s(s0, q[j],     p0);
      pk_fma_s(s1, q[j + 1], p1);
    }
    float pr = (s0.x + s0.y) + (s1.x + s1.y);      // (2*step*Q y)[r]

    // exchange the 128 matvec outputs; dbuf -> ONE barrier per iteration
    float* pb = pbuf[it & 1];
    pb[2 * lane + wid] = pr;
    __syncthreads();
    v2f pv = *(const v2f*)&pb[2 * lane];
    float v0 = ye - pv.x + r2e;                    // v = y - step*grad
    float v1 = yo - pv.y + r2o;

    // projection onto {sum w=1, 0<=w<=1}: 4 rounds x 4-point bracket search
    float mn = fminf(v0, v1), mx = fmaxf(v0, v1);
    wminmax(mn, mx);
    float lo = mn - 1.0f;
    float W  = mx - lo;
    #pragma unroll 1
    for (int r = 0; r < NROUND; ++r) {
      float h  = W * 0.2f;
      float t1v = lo + h, t2v = lo + 2.f*h, t3v = lo + 3.f*h, t4v = lo + 4.f*h;
      float sa = __builtin_amdgcn_fmed3f(v0 - t1v, 0.f, 1.f)
               + __builtin_amdgcn_fmed3f(v1 - t1v, 0.f, 1.f);
      float sb = __builtin_amdgcn_fmed3f(v0 - t2v, 0.f, 1.f)
               + __builtin_amdgcn_fmed3f(v1 - t2v, 0.f, 1.f);
      float sc4 = __builtin_amdgcn_fmed3f(v0 - t3v, 0.f, 1.f)
               + __builtin_amdgcn_fmed3f(v1 - t3v, 0.f, 1.f);
      float sd = __builtin_amdgcn_fmed3f(v0 - t4v, 0.f, 1.f)
               + __builtin_amdgcn_fmed3f(v1 - t4v, 0.f, 1.f);
      wsum4(sa, sb, sc4, sd);
      float cnt = ((sa > 1.f ? 1.f : 0.f) + (sb > 1.f ? 1.f : 0.f))
                + ((sc4 > 1.f ? 1.f : 0.f) + (sd > 1.f ? 1.f : 0.f));
      lo = fmaf(cnt, h, lo);
      W  = h;
    }
    float tauf = lo + 0.5f * W;

    // two exact active-set Newton steps; second also produces w
    float w0 = 0.f, w1 = 0.f;
    #pragma unroll
    for (int e = 0; e < 2; ++e) {
      float z0 = v0 - tauf, z1 = v1 - tauf;
      bool fr0 = (z0 > 0.f) && (z0 < 1.0f);
      bool fr1 = (z1 > 0.f) && (z1 < 1.0f);
      bool cp0 = (z0 >= 1.0f), cp1 = (z1 >= 1.0f);
      float sfv = (fr0 ? v0 : 0.f) + (fr1 ? v1 : 0.f);
      float cnt = (fr0 ? 1.f : 0.f) + (fr1 ? 1.f : 0.f)
                + 1024.f * ((cp0 ? 1.f : 0.f) + (cp1 ? 1.f : 0.f));
      wsum2(sfv, cnt);
      float nu    = floorf(cnt * (1.f / 1024.f));
      float nfree = fmaxf(cnt - 1024.f * nu, 1.f);
      tauf = (sfv + nu - 1.f) * __builtin_amdgcn_rcpf(nfree);
      if (e == 1) {
        w0 = fr0 ? (v0 - tauf) : (cp0 ? 1.0f : 0.f);
        w1 = fr1 ? (v1 - tauf) : (cp1 ? 1.0f : 0.f);
      }
    }

    // FISTA momentum (identical in both waves -> states stay bit-identical)
    float tn   = 0.5f * (1.f + sqrtf(1.f + 4.f * t_f * t_f));
    float coef = (t_f - 1.f) * __builtin_amdgcn_rcpf(tn);
    ye = w0 + coef * (w0 - wpe);
    yo = w1 + coef * (w1 - wpo);
    wpe = w0; wpo = w1;
    t_f = tn;
  }

  if (wid == 0) {
    v2f wv = { wpe, wpo };
    ((v2f*)out)[(size_t)b * 64 + lane] = wv;   // 8B coalesced store
  }
}

extern "C" void kernel_launch(void* const* d_in, const int* in_sizes, int n_in,
                              void* d_out, int out_size, void* d_ws, size_t ws_size,
                              hipStream_t stream) {
  (void)n_in; (void)d_ws; (void)ws_size; (void)out_size;
  const float* rets = (const float*)d_in[0];
  const float* cov  = (const float*)d_in[1];
  const float* gam  = (const float*)d_in[2];
  const float* alp  = (const float*)d_in[3];
  float* out = (float*)d_out;
  const int B = in_sizes[0] / NN;   // 1024 blocks x 2 waves = 2 waves/SIMD
  markowitz_kernel<<<B, 128, 0, stream>>>(rets, cov, gam, alp, out);
}

// Round 4
// 722.141 us; speedup vs baseline: 1.1963x; 1.1963x over previous
//
#include <hip/hip_runtime.h>

#define NN 128
#define NITER 300
// Projection = warm-started SAFEGUARDED Newton on s(tau)=sum(clip(v-tau,0,1)).
// Newton: tau' = (sum_free v + ncap - 1)/nfree. s is piecewise-linear,
// non-convex -> raw Newton can 2-cycle (R3 failure). Safeguard: maintain
// bracket [lo,hi] with s(lo)>1>s(hi); accept Newton only strictly inside,
// else bisect. Revisiting a bracket endpoint forces bisection -> cycles are
// impossible, bracket strictly shrinks -> convergent. Early-exit on
// |s-1|<=1e-5 (wave-uniform). Warm tau carried across FISTA iterations.

// ---- DPP wave-64 cross-lane helpers (R5-proven) ----
template<int CTRL>
__device__ __forceinline__ float dpp0(float x) {  // invalid lanes contribute 0
  return __int_as_float(__builtin_amdgcn_update_dpp(0, __float_as_int(x), CTRL, 0xF, 0xF, true));
}
template<int CTRL>
__device__ __forceinline__ float dppS(float x) {  // invalid lanes keep self
  int xi = __float_as_int(x);
  return __int_as_float(__builtin_amdgcn_update_dpp(xi, xi, CTRL, 0xF, 0xF, false));
}
__device__ __forceinline__ float bcast63(float x) {
  return __int_as_float(__builtin_amdgcn_readlane(__float_as_int(x), 63));
}
__device__ __forceinline__ float rlane(float x, int l) {   // l literal after unroll
  return __int_as_float(__builtin_amdgcn_readlane(__float_as_int(x), l));
}
__device__ __forceinline__ float wsum(float x) {
  x += dpp0<0x111>(x); x += dpp0<0x112>(x); x += dpp0<0x114>(x);
  x += dpp0<0x118>(x); x += dpp0<0x142>(x); x += dpp0<0x143>(x);
  return bcast63(x);
}
__device__ __forceinline__ void wsum2(float& x, float& y) {  // two interleaved chains
  float a = x, b = y;
  a += dpp0<0x111>(a); b += dpp0<0x111>(b);
  a += dpp0<0x112>(a); b += dpp0<0x112>(b);
  a += dpp0<0x114>(a); b += dpp0<0x114>(b);
  a += dpp0<0x118>(a); b += dpp0<0x118>(b);
  a += dpp0<0x142>(a); b += dpp0<0x142>(b);
  a += dpp0<0x143>(a); b += dpp0<0x143>(b);
  x = bcast63(a); y = bcast63(b);
}
__device__ __forceinline__ void wminmax(float& mn, float& mx) {  // interleaved
  mn = fminf(mn, dppS<0x111>(mn)); mx = fmaxf(mx, dppS<0x111>(mx));
  mn = fminf(mn, dppS<0x112>(mn)); mx = fmaxf(mx, dppS<0x112>(mx));
  mn = fminf(mn, dppS<0x114>(mn)); mx = fmaxf(mx, dppS<0x114>(mx));
  mn = fminf(mn, dppS<0x118>(mn)); mx = fmaxf(mx, dppS<0x118>(mx));
  mn = fminf(mn, dppS<0x142>(mn)); mx = fmaxf(mx, dppS<0x142>(mx));
  mn = fminf(mn, dppS<0x143>(mn)); mx = fmaxf(mx, dppS<0x143>(mx));
  mn = bcast63(mn); mx = bcast63(mx);
}

// ONE WAVE PER SAMPLE (R0/R5 structure — proven best). Lane owns rows
// {lane, lane+64}. Plain-C scalar FMA (no inline asm).
__launch_bounds__(64, 1)
__global__ void markowitz_kernel(const float* __restrict__ rets,
                                 const float* __restrict__ cov,
                                 const float* __restrict__ gam,
                                 const float* __restrict__ alp,
                                 float* __restrict__ out)
{
  const int b    = blockIdx.x;
  const int lane = threadIdx.x;          // block = exactly one wave (64)

  const float g   = gam[b];
  const float g2  = g * g;
  const float aab = fabsf(alp[b]);
  const float* cb = cov + (size_t)b * (NN * NN);

  // ---------- build Q = g2*C^T C + aab*I (rows lane / lane+64) ----------
  float accA[NN], accB[NN];
  #pragma unroll
  for (int u = 0; u < NN; ++u) { accA[u] = 0.f; accB[u] = 0.f; }

  const float* ap0 = cb + lane;
  const float* ap1 = cb + lane + 64;
  #pragma unroll 2
  for (int k = 0; k < NN; ++k) {
    float a0 = ap0[(size_t)k * NN];      // C[k][lane]      (coalesced)
    float a1 = ap1[(size_t)k * NN];      // C[k][lane+64]
    #pragma unroll
    for (int u = 0; u < 64; ++u) {
      float s0 = rlane(a0, u);           // C[k][u]
      float s1 = rlane(a1, u);           // C[k][64+u]
      accA[u]      = fmaf(a0, s0, accA[u]);
      accA[64 + u] = fmaf(a0, s1, accA[64 + u]);
      accB[u]      = fmaf(a1, s0, accB[u]);
      accB[64 + u] = fmaf(a1, s1, accB[64 + u]);
    }
  }

  // scale, diagonal, Frobenius^2 (4 partial chains)
  float ss0 = 0.f, ss1 = 0.f, ss2 = 0.f, ss3 = 0.f;
  #pragma unroll
  for (int u = 0; u < NN; ++u) {
    float qa = g2 * accA[u]; if (u == lane)      qa += aab;
    float qb = g2 * accB[u]; if (u == lane + 64) qb += aab;
    accA[u] = qa; accB[u] = qb;
    if (u & 1) { ss0 = fmaf(qa, qa, ss0); ss1 = fmaf(qb, qb, ss1); }
    else       { ss2 = fmaf(qa, qa, ss2); ss3 = fmaf(qb, qb, ss3); }
  }
  const float S    = wsum((ss0 + ss2) + (ss1 + ss3));
  const float step = 0.5f / sqrtf(S);    // 1/(2||Q||_F)
  const float sc   = 2.f * step;
  #pragma unroll
  for (int u = 0; u < NN; ++u) { accA[u] *= sc; accB[u] *= sc; }  // acc = 2*step*Q

  const float r2a = step * rets[b * NN + lane];
  const float r2b = step * rets[b * NN + 64 + lane];

  // ---------- FISTA, fully in-wave ----------
  float y0 = 1.f / 128.f, y1 = 1.f / 128.f;   // y coords (lane, lane+64)
  float w0p = y0, w1p = y1;                   // w_prev
  float t_f = 1.f;
  float tau = 0.f;                            // warm-started dual variable

  #pragma unroll 1
  for (int it = 0; it < NITER; ++it) {
    // matvec: 4 independent fma chains, y broadcast via readlane (R5-proven)
    float pA0 = 0.f, pA1 = 0.f, pB0 = 0.f, pB1 = 0.f;
    #pragma unroll
    for (int u = 0; u < 64; ++u) {
      float t0 = rlane(y0, u);
      float t1 = rlane(y1, u);
      pA0 = fmaf(accA[u],      t0, pA0);
      pA1 = fmaf(accA[64 + u], t1, pA1);
      pB0 = fmaf(accB[u],      t0, pB0);
      pB1 = fmaf(accB[64 + u], t1, pB1);
    }
    float v0 = y0 - (pA0 + pA1) + r2a;   // v = y - step*grad
    float v1 = y1 - (pB0 + pB1) + r2b;

    // ---- projection: bracket + warm-started safeguarded Newton ----
    float mn = fminf(v0, v1), mx = fmaxf(v0, v1);
    wminmax(mn, mx);
    float lo = mn - 1.0f;                // s(lo) = 128 > 1
    float hi = mx;                       // s(hi) = 0   < 1
    tau = fminf(fmaxf(tau, lo), hi);
    const int emax = (it == 0) ? 12 : 6;

    #pragma unroll 1
    for (int e = 0; e < emax; ++e) {
      float z0 = v0 - tau, z1 = v1 - tau;
      bool fr0 = (z0 > 0.f) && (z0 < 1.0f);
      bool fr1 = (z1 > 0.f) && (z1 < 1.0f);
      bool cp0 = (z0 >= 1.0f), cp1 = (z1 >= 1.0f);
      float sfv = (fr0 ? v0 : 0.f) + (fr1 ? v1 : 0.f);
      float cnt = (fr0 ? 1.f : 0.f) + (fr1 ? 1.f : 0.f)
                + 1024.f * ((cp0 ? 1.f : 0.f) + (cp1 ? 1.f : 0.f));
      wsum2(sfv, cnt);
      float nu    = floorf(cnt * (1.f / 1024.f));     // ncap
      float nfree = cnt - 1024.f * nu;                // true nfree (may be 0)
      float s     = fmaf(-nfree, tau, sfv) + nu;      // s(tau)
      if (fabsf(s - 1.f) <= 1e-5f) break;             // wave-uniform exit
      if (s > 1.f) lo = tau; else hi = tau;           // shrink bracket
      float taun = (sfv + nu - 1.f) * __builtin_amdgcn_rcpf(fmaxf(nfree, 1.f));
      bool ok = (nfree >= 0.5f) && (taun > lo) && (taun < hi);
      tau = ok ? taun : 0.5f * (lo + hi);
    }

    // derive stage (reference semantics): sets at tau -> exact tau -> w
    float z0 = v0 - tau, z1 = v1 - tau;
    bool fr0 = (z0 > 0.f) && (z0 < 1.0f);
    bool fr1 = (z1 > 0.f) && (z1 < 1.0f);
    bool cp0 = (z0 >= 1.0f), cp1 = (z1 >= 1.0f);
    float sfv = (fr0 ? v0 : 0.f) + (fr1 ? v1 : 0.f);
    float cnt = (fr0 ? 1.f : 0.f) + (fr1 ? 1.f : 0.f)
              + 1024.f * ((cp0 ? 1.f : 0.f) + (cp1 ? 1.f : 0.f));
    wsum2(sfv, cnt);
    float nu    = floorf(cnt * (1.f / 1024.f));
    float nfree = fmaxf(cnt - 1024.f * nu, 1.f);
    tau = (sfv + nu - 1.f) * __builtin_amdgcn_rcpf(nfree);   // exact on fixed set
    float w0 = fr0 ? (v0 - tau) : (cp0 ? 1.0f : 0.f);
    float w1 = fr1 ? (v1 - tau) : (cp1 ? 1.0f : 0.f);

    // FISTA momentum
    float tn   = 0.5f * (1.f + sqrtf(1.f + 4.f * t_f * t_f));
    float coef = (t_f - 1.f) * __builtin_amdgcn_rcpf(tn);
    y0 = w0 + coef * (w0 - w0p);
    y1 = w1 + coef * (w1 - w1p);
    w0p = w0; w1p = w1;
    t_f = tn;
  }

  out[(size_t)b * NN + lane]      = w0p;
  out[(size_t)b * NN + 64 + lane] = w1p;
}

extern "C" void kernel_launch(void* const* d_in, const int* in_sizes, int n_in,
                              void* d_out, int out_size, void* d_ws, size_t ws_size,
                              hipStream_t stream) {
  (void)n_in; (void)d_ws; (void)ws_size; (void)out_size;
  const float* rets = (const float*)d_in[0];
  const float* cov  = (const float*)d_in[1];
  const float* gam  = (const float*)d_in[2];
  const float* alp  = (const float*)d_in[3];
  float* out = (float*)d_out;
  const int B = in_sizes[0] / NN;   // 1024 waves, one sample each
  markowitz_kernel<<<B, 64, 0, stream>>>(rets, cov, gam, alp, out);
}